// Round 1
// baseline (79.663 us; speedup 1.0000x reference)
//
#include <hip/hip_runtime.h>

// 1x1 conv (NHWC, 512->32, no bias) + tanh + sign  ==  sign(x @ W)
// x: [M=131072, K=512] f32 row-major, W: [K=512, N=32] f32, out: [M, N] f32 in {-1,0,1}
//
// Main pass: f32 register-tiled GEMM (4 rows x 8 cols / thread).
// Any |acc| < TAU (worst-case f32 error ~1e-4 << TAU=1e-3) is recomputed
// exactly in f64 by the whole wave (coalesced row read + shuffle reduce),
// so the emitted sign is the true sign of the dot product.

constexpr int K      = 512;
constexpr int N      = 32;
constexpr int BROWS  = 256;          // rows per block
constexpr int KC     = 32;           // k-chunk
constexpr int XSTR   = KC + 4;       // 36 floats = 144 B row stride (16B aligned, breaks conflicts)
constexpr float TAU  = 1e-3f;

__global__ __launch_bounds__(256)
void conv_sign_kernel(const float* __restrict__ x,
                      const float* __restrict__ Wm,
                      float* __restrict__ out, int M)
{
    __shared__ float xs[BROWS * XSTR];   // 36 KiB
    __shared__ float ws[KC * N];         //  4 KiB

    const int t         = threadIdx.x;
    const int lane      = t & 63;
    const int wave      = t >> 6;
    const int block_row = blockIdx.x * BROWS;

    const int r0 = (t >> 2) * 4;         // local row base (4 rows per thread)
    const int c0 = (t & 3) * 8;          // col base (8 cols per thread)

    float acc[4][8];
#pragma unroll
    for (int i = 0; i < 4; ++i)
#pragma unroll
        for (int j = 0; j < 8; ++j) acc[i][j] = 0.f;

    const int sr = t >> 3;               // staging: row within 32-row pass
    const int sk = (t & 7) * 4;          // staging: float4 k-offset (8 lanes = 128 B/row)

    for (int kc = 0; kc < K; kc += KC) {
        __syncthreads();                 // previous chunk's compute done
        // stage W chunk [KC][N] = 1024 contiguous floats
        {
            float4 w4 = *reinterpret_cast<const float4*>(Wm + kc * N + t * 4);
            *reinterpret_cast<float4*>(ws + t * 4) = w4;
        }
        // stage x chunk: 256 rows x 32 floats (128 B contiguous per row per wave-octet)
#pragma unroll
        for (int p = 0; p < 8; ++p) {
            int row  = p * 32 + sr;
            int grow = block_row + row;
            float4 v = *reinterpret_cast<const float4*>(x + (size_t)grow * K + kc + sk);
            *reinterpret_cast<float4*>(xs + row * XSTR + sk) = v;
        }
        __syncthreads();                 // staging visible

#pragma unroll
        for (int kk = 0; kk < KC; kk += 4) {
            float4 xv[4];
#pragma unroll
            for (int i = 0; i < 4; ++i)
                xv[i] = *reinterpret_cast<const float4*>(xs + (r0 + i) * XSTR + kk);
#pragma unroll
            for (int j = 0; j < 4; ++j) {
                float4 w0 = *reinterpret_cast<const float4*>(ws + (kk + j) * N + c0);
                float4 w1 = *reinterpret_cast<const float4*>(ws + (kk + j) * N + c0 + 4);
#pragma unroll
                for (int i = 0; i < 4; ++i) {
                    float xr = (&xv[i].x)[j];
                    acc[i][0] += xr * w0.x;
                    acc[i][1] += xr * w0.y;
                    acc[i][2] += xr * w0.z;
                    acc[i][3] += xr * w0.w;
                    acc[i][4] += xr * w1.x;
                    acc[i][5] += xr * w1.y;
                    acc[i][6] += xr * w1.z;
                    acc[i][7] += xr * w1.w;
                }
            }
        }
    }

    // --- exact f64 fixup for ambiguous accumulators (|acc| < TAU) ---
#pragma unroll
    for (int ai = 0; ai < 4; ++ai) {
#pragma unroll
        for (int bi = 0; bi < 8; ++bi) {
            unsigned long long bal = __ballot(fabsf(acc[ai][bi]) < TAU);
            while (bal) {
                int s = __ffsll(bal) - 1;
                bal &= bal - 1;
                // (row, col) owned by lane s for this (ai, bi)
                int gr = block_row + wave * 64 + ((s >> 2) << 2) + ai;
                int gc = ((s & 3) << 3) + bi;
                // whole wave recomputes the dot in f64: lane covers k = lane*8 .. +8
                const float* xr = x  + (size_t)gr * K + lane * 8;
                const float* wr = Wm + (size_t)(lane * 8) * N + gc;
                double part = 0.0;
#pragma unroll
                for (int q = 0; q < 8; ++q)
                    part += (double)xr[q] * (double)wr[q * N];
#pragma unroll
                for (int off = 32; off > 0; off >>= 1)
                    part += __shfl_xor(part, off);
                if (lane == s)
                    acc[ai][bi] = (part > 0.0) ? 2.f : ((part < 0.0) ? -2.f : 0.f);
            }
        }
    }

    // --- sign + store (4 lanes cover one 128 B output row) ---
#pragma unroll
    for (int i = 0; i < 4; ++i) {
        int gr = block_row + r0 + i;
        float o[8];
#pragma unroll
        for (int j = 0; j < 8; ++j) {
            float v = acc[i][j];
            o[j] = (v > 0.f) ? 1.f : ((v < 0.f) ? -1.f : 0.f);
        }
        float4* dst = reinterpret_cast<float4*>(out + (size_t)gr * N + c0);
        dst[0] = make_float4(o[0], o[1], o[2], o[3]);
        dst[1] = make_float4(o[4], o[5], o[6], o[7]);
    }
}

extern "C" void kernel_launch(void* const* d_in, const int* in_sizes, int n_in,
                              void* d_out, int out_size, void* d_ws, size_t ws_size,
                              hipStream_t stream)
{
    const float* x  = (const float*)d_in[0];
    const float* Wm = (const float*)d_in[1];
    float* out      = (float*)d_out;
    const int M     = in_sizes[0] / K;        // 131072
    const int grid  = (M + BROWS - 1) / BROWS; // 512
    hipLaunchKernelGGL(conv_sign_kernel, dim3(grid), dim3(256), 0, stream,
                       x, Wm, out, M);
}